// Round 1
// baseline (564.169 us; speedup 1.0000x reference)
//
#include <hip/hip_runtime.h>

typedef unsigned short u16;
typedef __bf16  bf16x8 __attribute__((ext_vector_type(8)));
typedef float   f32x4  __attribute__((ext_vector_type(4)));
typedef u16     u16x8  __attribute__((ext_vector_type(8)));
typedef u16     u16x4  __attribute__((ext_vector_type(4)));

// ---------------------------------------------------------------------------
// helpers
// ---------------------------------------------------------------------------
__device__ __forceinline__ u16 f2b(float f) {               // f32 -> bf16 (RNE)
    unsigned u = __float_as_uint(f);
    unsigned r = u + 0x7FFFu + ((u >> 16) & 1u);
    return (u16)(r >> 16);
}
__device__ __forceinline__ float b2f(u16 b) {
    return __uint_as_float(((unsigned)b) << 16);
}
__device__ __forceinline__ void async16(const u16* g, u16* l) {
    // lane L's 16B land at (wave-uniform l) + L*16
    __builtin_amdgcn_global_load_lds(
        (__attribute__((address_space(1))) void*)(u16*)g,
        (__attribute__((address_space(3))) void*)l, 16, 0, 0);
}

// ---------------------------------------------------------------------------
// fp32 -> bf16 convert (float4 per thread)
// ---------------------------------------------------------------------------
__global__ void cvt_f32_bf16(const float* __restrict__ in, u16* __restrict__ out, int n4) {
    int i = blockIdx.x * blockDim.x + threadIdx.x;
    if (i >= n4) return;
    float4 f = ((const float4*)in)[i];
    u16x4 o;
    o[0] = f2b(f.x); o[1] = f2b(f.y); o[2] = f2b(f.z); o[3] = f2b(f.w);
    *(u16x4*)(out + (size_t)i * 4) = o;
}

// ---------------------------------------------------------------------------
// bf16 NT GEMM: C[M,N] = A[M,K] * B[N,K]^T + bias   (128x128 tile, BK=32)
// mode 0: store bf16 row-major [M][N]
// mode 1: store f32 with row remap orow = (row&1)*2048 + (row>>1)  (final out)
// ---------------------------------------------------------------------------
__global__ __launch_bounds__(256) void gemm_bt(
    const u16* __restrict__ A, const u16* __restrict__ B,
    const float* __restrict__ bias, void* __restrict__ C,
    int M, int N, int K, int mode)
{
    __shared__ u16 As[128 * 32];
    __shared__ u16 Bs[128 * 32];
    int tid = threadIdx.x, wave = tid >> 6, lane = tid & 63;
    int lg = lane >> 4, lm = lane & 15;
    int wm = (wave & 1) * 64, wn = (wave >> 1) * 64;

    const u16* Ab = A + (size_t)(blockIdx.y * 128) * K;
    const u16* Bb = B + (size_t)(blockIdx.x * 128) * K;

    f32x4 acc[4][4];
    for (int i = 0; i < 4; i++)
        for (int j = 0; j < 4; j++)
            acc[i][j] = (f32x4){0.f, 0.f, 0.f, 0.f};

    int srow = (lane >> 2), skq = (lane & 3) * 8;   // staging: lane -> row/k within 1KB chunk

    for (int k0 = 0; k0 < K; k0 += 32) {
        __syncthreads();
        for (int c = wave; c < 8; c += 4) {
            int row = c * 16 + srow;
            async16(Ab + (size_t)row * K + k0 + skq, &As[c * 512]);
            async16(Bb + (size_t)row * K + k0 + skq, &Bs[c * 512]);
        }
        __syncthreads();   // compiler drains vmcnt before barrier

        bf16x8 af[4], bf[4];
        for (int i = 0; i < 4; i++) af[i] = *(const bf16x8*)&As[(wm + i * 16 + lm) * 32 + lg * 8];
        for (int j = 0; j < 4; j++) bf[j] = *(const bf16x8*)&Bs[(wn + j * 16 + lm) * 32 + lg * 8];
        for (int i = 0; i < 4; i++)
            for (int j = 0; j < 4; j++)
                acc[i][j] = __builtin_amdgcn_mfma_f32_16x16x32_bf16(af[i], bf[j], acc[i][j], 0, 0, 0);
    }

    for (int j = 0; j < 4; j++) {
        int col = blockIdx.x * 128 + wn + j * 16 + lm;
        float bv = bias[col];
        for (int i = 0; i < 4; i++) {
            int row0 = blockIdx.y * 128 + wm + i * 16 + lg * 4;
            for (int r = 0; r < 4; r++) {
                float v = acc[i][j][r] + bv;
                int row = row0 + r;
                if (mode == 0) {
                    ((u16*)C)[(size_t)row * N + col] = f2b(v);
                } else {
                    int orow = ((row & 1) << 11) + (row >> 1);
                    ((float*)C)[(size_t)orow * N + col] = v;
                }
            }
        }
    }
}

// ---------------------------------------------------------------------------
// scatter mixed[b,s,nh,3*128] -> qb/kb [bn][pos][hd]  (bn=(s&1)*16+nh, pos=b*1024+s/2)
// part 0 = q (pre-scaled by 1/sqrt(128)), part 1 = k
// ---------------------------------------------------------------------------
__global__ void scatter_qk(const u16* __restrict__ mixed,
                           u16* __restrict__ qb, u16* __restrict__ kb)
{
    int part = blockIdx.y;
    int t = blockIdx.x * 256 + threadIdx.x;      // 32*2048*16 total
    int hd8 = t & 15;
    int pos = (t >> 4) & 2047;
    int bn  = t >> 15;
    int b = pos >> 10, s = ((pos & 1023) << 1) | (bn >> 4), nh = bn & 15;
    const u16* src = mixed + (size_t)(b * 2048 + s) * 6144 + nh * 384 + part * 128 + hd8 * 8;
    u16x8 v = *(const u16x8*)src;
    if (part == 0) {
        for (int j = 0; j < 8; j++)
            v[j] = f2b(b2f(v[j]) * 0.08838834764831845f);   // 1/sqrt(128)
    }
    u16* dst = (part ? kb : qb) + (size_t)(bn * 2048 + pos) * 128 + hd8 * 8;
    *(u16x8*)dst = v;
}

// ---------------------------------------------------------------------------
// v: mixed -> vb [bn][hd][pos]  (transposed for PV B-operand ds_read_b128)
// one block per (bn, 64-pos tile)
// ---------------------------------------------------------------------------
__global__ __launch_bounds__(256) void transpose_v(const u16* __restrict__ mixed,
                                                   u16* __restrict__ vb)
{
    __shared__ u16 tile[64][144];
    int bn = blockIdx.x >> 5, pt = blockIdx.x & 31;
    int p0 = pt * 64;
    int t = threadIdx.x;
    int nh = bn & 15;
    int hd8 = t & 15, pr = t >> 4;
    for (int i = 0; i < 4; i++) {
        int p = pr + i * 16;
        int pos = p0 + p;
        int b = pos >> 10, s = ((pos & 1023) << 1) | (bn >> 4);
        const u16* src = mixed + (size_t)(b * 2048 + s) * 6144 + nh * 384 + 256 + hd8 * 8;
        *(u16x8*)&tile[p][hd8 * 8] = *(const u16x8*)src;
    }
    __syncthreads();
    int hd = t >> 1, h2 = (t & 1) * 32;
    u16 tmp[32];
    for (int j = 0; j < 32; j++) tmp[j] = tile[h2 + j][hd];
    u16* dst = vb + (size_t)(bn * 128 + hd) * 2048 + p0 + h2;
    for (int i = 0; i < 4; i++) *(u16x8*)(dst + i * 8) = *(const u16x8*)&tmp[i * 8];
}

// ---------------------------------------------------------------------------
// flash attention in scrambled (bn, pos) space, causal, alibi[bn&15][k]
// block = 4 waves, Q tile 64 rows (16/wave), K tiles of 64
// writes ctx bf16 [pos*2 + bn>>4][ (bn&15)*128 + hd ]  (rows of dense GEMM)
// ---------------------------------------------------------------------------
__global__ __launch_bounds__(256) void attn(
    const u16* __restrict__ qb, const u16* __restrict__ kb,
    const u16* __restrict__ vb, const float* __restrict__ alibi,
    u16* __restrict__ ctx)
{
    __shared__ u16 Ks[64 * 136];    // K tile [k][hd], pad 136
    __shared__ u16 Vt[128 * 88];    // V^T tile [hd][k], pad 88
    __shared__ u16 Ps[64 * 80];     // P tile [q][k], pad 80

    int qt = blockIdx.x, bn = blockIdx.y;
    int q0 = qt * 64;
    int tid = threadIdx.x, wave = tid >> 6, lane = tid & 63;
    int lg = lane >> 4, lm = lane & 15;

    // Q fragments (pre-scaled bf16), wave owns rows q0+16w .. +15
    bf16x8 qf[4];
    {
        const u16* qp = qb + (size_t)(bn * 2048 + q0 + wave * 16 + lm) * 128;
        for (int kc = 0; kc < 4; kc++) qf[kc] = *(const bf16x8*)(qp + kc * 32 + lg * 8);
    }

    f32x4 o[8];
    for (int i = 0; i < 8; i++) o[i] = (f32x4){0.f, 0.f, 0.f, 0.f};
    float m_i[4] = {-3e38f, -3e38f, -3e38f, -3e38f};
    float l_i[4] = {0.f, 0.f, 0.f, 0.f};
    const float* al = alibi + (bn & 15) * 2048;

    int krow = tid >> 2, kq = (tid & 3) * 32;
    int vhd  = tid >> 1, vh2 = (tid & 1) * 32;
    const u16* ksrc0 = kb + (size_t)(bn * 2048 + krow) * 128 + kq;
    const u16* vsrc0 = vb + (size_t)(bn * 128 + vhd) * 2048 + vh2;

    for (int kt = 0; kt <= qt; kt++) {
        int k0 = kt * 64;
        __syncthreads();
        {   // stage K [64][128] and V^T [128][64]
            const u16* s1 = ksrc0 + (size_t)k0 * 128;
            u16* d1 = &Ks[krow * 136 + kq];
            for (int i = 0; i < 4; i++) *(u16x8*)(d1 + i * 8) = *(const u16x8*)(s1 + i * 8);
            const u16* s2 = vsrc0 + k0;
            u16* d2 = &Vt[vhd * 88 + vh2];
            for (int i = 0; i < 4; i++) *(u16x8*)(d2 + i * 8) = *(const u16x8*)(s2 + i * 8);
        }
        __syncthreads();

        // S = Qs * K^T  (per wave: 16 q rows x 64 k cols)
        f32x4 sc[4];
        for (int tc = 0; tc < 4; tc++) {
            f32x4 a = (f32x4){0.f, 0.f, 0.f, 0.f};
            const u16* kr = &Ks[(tc * 16 + lm) * 136];
            for (int kc = 0; kc < 4; kc++) {
                bf16x8 bfr = *(const bf16x8*)(kr + kc * 32 + lg * 8);
                a = __builtin_amdgcn_mfma_f32_16x16x32_bf16(qf[kc], bfr, a, 0, 0, 0);
            }
            sc[tc] = a;
        }
        // alibi + causal mask
        for (int tc = 0; tc < 4; tc++) {
            int kg = k0 + tc * 16 + lm;
            float av = al[kg];
            for (int r = 0; r < 4; r++) {
                float v = sc[tc][r] + av;
                if (kt == qt) {
                    int qg = q0 + wave * 16 + lg * 4 + r;
                    if (kg > qg) v = -3e38f;
                }
                sc[tc][r] = v;
            }
        }
        // online softmax (row lives in 16 consecutive lanes, same lg)
        float alpha[4];
        for (int r = 0; r < 4; r++) {
            float t = fmaxf(fmaxf(sc[0][r], sc[1][r]), fmaxf(sc[2][r], sc[3][r]));
            t = fmaxf(t, __shfl_xor(t, 1));
            t = fmaxf(t, __shfl_xor(t, 2));
            t = fmaxf(t, __shfl_xor(t, 4));
            t = fmaxf(t, __shfl_xor(t, 8));
            float mn = fmaxf(m_i[r], t);
            alpha[r] = __expf(m_i[r] - mn);
            m_i[r] = mn;
        }
        for (int r = 0; r < 4; r++) {
            float rs = 0.f;
            for (int tc = 0; tc < 4; tc++) {
                float p = __expf(sc[tc][r] - m_i[r]);
                sc[tc][r] = p;
                rs += p;
            }
            rs += __shfl_xor(rs, 1);
            rs += __shfl_xor(rs, 2);
            rs += __shfl_xor(rs, 4);
            rs += __shfl_xor(rs, 8);
            l_i[r] = l_i[r] * alpha[r] + rs;
        }
        for (int i = 0; i < 8; i++)
            for (int r = 0; r < 4; r++) o[i][r] *= alpha[r];

        // P -> LDS (C/D layout -> A-operand layout round trip)
        for (int tc = 0; tc < 4; tc++)
            for (int r = 0; r < 4; r++)
                Ps[(wave * 16 + lg * 4 + r) * 80 + tc * 16 + lm] = f2b(sc[tc][r]);
        __syncthreads();

        // O += P * V
        for (int kc = 0; kc < 2; kc++) {
            bf16x8 pf = *(const bf16x8*)&Ps[(wave * 16 + lm) * 80 + kc * 32 + lg * 8];
            for (int i = 0; i < 8; i++) {
                bf16x8 vf = *(const bf16x8*)&Vt[(i * 16 + lm) * 88 + kc * 32 + lg * 8];
                o[i] = __builtin_amdgcn_mfma_f32_16x16x32_bf16(pf, vf, o[i], 0, 0, 0);
            }
        }
    }

    // epilogue: ctx[pos*2 + b'][ nh'*128 + hd ]  (reference keeps scrambled coords)
    for (int r = 0; r < 4; r++) {
        float inv = 1.0f / l_i[r];
        int qg = q0 + wave * 16 + lg * 4 + r;
        int row = qg * 2 + (bn >> 4);
        u16* crow = ctx + (size_t)row * 2048 + (bn & 15) * 128;
        for (int i = 0; i < 8; i++)
            crow[i * 16 + lm] = f2b(o[i][r] * inv);
    }
}

// ---------------------------------------------------------------------------
// launch
// ---------------------------------------------------------------------------
extern "C" void kernel_launch(void* const* d_in, const int* in_sizes, int n_in,
                              void* d_out, int out_size, void* d_ws, size_t ws_size,
                              hipStream_t stream)
{
    const float* hs    = (const float*)d_in[0];   // [2,2048,2048]
    const float* alibi = (const float*)d_in[1];   // [16,1,2048]
    const float* wqkv  = (const float*)d_in[2];   // [6144,2048]
    const float* bqkv  = (const float*)d_in[3];   // [6144]
    const float* wd    = (const float*)d_in[4];   // [2048,2048]
    const float* bd    = (const float*)d_in[5];   // [2048]
    float* out = (float*)d_out;                   // [2,2048,2048] f32

    char* ws = (char*)d_ws;
    u16* wqkv_b = (u16*)(ws + 0);            // 12,582,912 elems (25,165,824 B)
    u16* hs_b   = (u16*)(ws + 25165824);     //  8,388,608 elems (16,777,216 B)
    u16* mixed  = (u16*)(ws + 41943040);     // 25,165,824 elems (50,331,648 B)
    u16* ctx    = mixed;                     // alias: mixed dead after scatter
    u16* wd_b   = wqkv_b;                    // alias: wqkv dead after gemm1
    u16* qb     = (u16*)(ws + 92274688);     // [32][2048][128] bf16
    u16* kb     = (u16*)(ws + 109051904);
    u16* vb     = (u16*)(ws + 125829120);    // end = 142,606,336 B

    cvt_f32_bf16<<<8192,  256, 0, stream>>>(hs,   hs_b,   2097152);
    cvt_f32_bf16<<<12288, 256, 0, stream>>>(wqkv, wqkv_b, 3145728);

    // mixed = hs @ wqkv^T + bqkv   (M=4096, N=6144, K=2048)
    gemm_bt<<<dim3(48, 32), 256, 0, stream>>>(hs_b, wqkv_b, bqkv, mixed, 4096, 6144, 2048, 0);

    scatter_qk<<<dim3(4096, 2), 256, 0, stream>>>(mixed, qb, kb);
    transpose_v<<<1024, 256, 0, stream>>>(mixed, vb);
    cvt_f32_bf16<<<4096, 256, 0, stream>>>(wd, wd_b, 1048576);

    attn<<<dim3(32, 32), 256, 0, stream>>>(qb, kb, vb, alibi, ctx);

    // out = ctx @ wd^T + bd, rows remapped to [b][s][h]   (M=4096, N=2048, K=2048)
    gemm_bt<<<dim3(16, 32), 256, 0, stream>>>(ctx, wd_b, bd, out, 4096, 2048, 2048, 1);
}

// Round 2
// 534.470 us; speedup vs baseline: 1.0556x; 1.0556x over previous
//
#include <hip/hip_runtime.h>

typedef unsigned short u16;
typedef __bf16  bf16x8 __attribute__((ext_vector_type(8)));
typedef float   f32x4  __attribute__((ext_vector_type(4)));
typedef u16     u16x8  __attribute__((ext_vector_type(8)));
typedef u16     u16x4  __attribute__((ext_vector_type(4)));

// ---------------------------------------------------------------------------
// helpers
// ---------------------------------------------------------------------------
__device__ __forceinline__ u16 f2b(float f) {               // f32 -> bf16 (RNE)
    unsigned u = __float_as_uint(f);
    unsigned r = u + 0x7FFFu + ((u >> 16) & 1u);
    return (u16)(r >> 16);
}
__device__ __forceinline__ float b2f(u16 b) {
    return __uint_as_float(((unsigned)b) << 16);
}
__device__ __forceinline__ void async16(const u16* g, u16* l) {
    // lane L's 16B land at (wave-uniform l) + L*16
    __builtin_amdgcn_global_load_lds(
        (__attribute__((address_space(1))) void*)(u16*)g,
        (__attribute__((address_space(3))) void*)l, 16, 0, 0);
}

// ---------------------------------------------------------------------------
// fp32 -> bf16 convert (float4 per thread)
// ---------------------------------------------------------------------------
__global__ void cvt_f32_bf16(const float* __restrict__ in, u16* __restrict__ out, int n4) {
    int i = blockIdx.x * blockDim.x + threadIdx.x;
    if (i >= n4) return;
    float4 f = ((const float4*)in)[i];
    u16x4 o;
    o[0] = f2b(f.x); o[1] = f2b(f.y); o[2] = f2b(f.z); o[3] = f2b(f.w);
    *(u16x4*)(out + (size_t)i * 4) = o;
}

// ---------------------------------------------------------------------------
// bf16 NT GEMM: C[M,N] = A[M,K] * B[N,K]^T + bias   (128x128 tile, BK=32)
// mode 0: store bf16 row-major [M][N]
// mode 1: store f32 with row remap orow = (row&1)*2048 + (row>>1)  (final out)
// ---------------------------------------------------------------------------
__global__ __launch_bounds__(256) void gemm_bt(
    const u16* __restrict__ A, const u16* __restrict__ B,
    const float* __restrict__ bias, void* __restrict__ C,
    int M, int N, int K, int mode)
{
    __shared__ u16 As[128 * 32];
    __shared__ u16 Bs[128 * 32];
    int tid = threadIdx.x, wave = tid >> 6, lane = tid & 63;
    int lg = lane >> 4, lm = lane & 15;
    int wm = (wave & 1) * 64, wn = (wave >> 1) * 64;

    const u16* Ab = A + (size_t)(blockIdx.y * 128) * K;
    const u16* Bb = B + (size_t)(blockIdx.x * 128) * K;

    f32x4 acc[4][4];
    for (int i = 0; i < 4; i++)
        for (int j = 0; j < 4; j++)
            acc[i][j] = (f32x4){0.f, 0.f, 0.f, 0.f};

    int srow = (lane >> 2), skq = (lane & 3) * 8;   // staging: lane -> row/k within 1KB chunk

    for (int k0 = 0; k0 < K; k0 += 32) {
        __syncthreads();
        for (int c = wave; c < 8; c += 4) {
            int row = c * 16 + srow;
            async16(Ab + (size_t)row * K + k0 + skq, &As[c * 512]);
            async16(Bb + (size_t)row * K + k0 + skq, &Bs[c * 512]);
        }
        __syncthreads();   // compiler drains vmcnt before barrier

        bf16x8 af[4], bf[4];
        for (int i = 0; i < 4; i++) af[i] = *(const bf16x8*)&As[(wm + i * 16 + lm) * 32 + lg * 8];
        for (int j = 0; j < 4; j++) bf[j] = *(const bf16x8*)&Bs[(wn + j * 16 + lm) * 32 + lg * 8];
        for (int i = 0; i < 4; i++)
            for (int j = 0; j < 4; j++)
                acc[i][j] = __builtin_amdgcn_mfma_f32_16x16x32_bf16(af[i], bf[j], acc[i][j], 0, 0, 0);
    }

    for (int j = 0; j < 4; j++) {
        int col = blockIdx.x * 128 + wn + j * 16 + lm;
        float bv = bias[col];
        for (int i = 0; i < 4; i++) {
            int row0 = blockIdx.y * 128 + wm + i * 16 + lg * 4;
            for (int r = 0; r < 4; r++) {
                float v = acc[i][j][r] + bv;
                int row = row0 + r;
                if (mode == 0) {
                    ((u16*)C)[(size_t)row * N + col] = f2b(v);
                } else {
                    int orow = ((row & 1) << 11) + (row >> 1);
                    ((float*)C)[(size_t)orow * N + col] = v;
                }
            }
        }
    }
}

// ---------------------------------------------------------------------------
// scatter mixed[b,s,nh,3*128] -> qb/kb [bn][pos][hd]  (bn=(s&1)*16+nh, pos=b*1024+s/2)
// part 0 = q (pre-scaled by 1/sqrt(128)), part 1 = k
// ---------------------------------------------------------------------------
__global__ void scatter_qk(const u16* __restrict__ mixed,
                           u16* __restrict__ qb, u16* __restrict__ kb)
{
    int part = blockIdx.y;
    int t = blockIdx.x * 256 + threadIdx.x;      // 32*2048*16 total
    int hd8 = t & 15;
    int pos = (t >> 4) & 2047;
    int bn  = t >> 15;
    int b = pos >> 10, s = ((pos & 1023) << 1) | (bn >> 4), nh = bn & 15;
    const u16* src = mixed + (size_t)(b * 2048 + s) * 6144 + nh * 384 + part * 128 + hd8 * 8;
    u16x8 v = *(const u16x8*)src;
    if (part == 0) {
        for (int j = 0; j < 8; j++)
            v[j] = f2b(b2f(v[j]) * 0.08838834764831845f);   // 1/sqrt(128)
    }
    u16* dst = (part ? kb : qb) + (size_t)(bn * 2048 + pos) * 128 + hd8 * 8;
    *(u16x8*)dst = v;
}

// ---------------------------------------------------------------------------
// v: mixed -> vb [bn][hd][pos]  (transposed for PV B-operand ds_read_b128)
// one block per (bn, 64-pos tile)
// ---------------------------------------------------------------------------
__global__ __launch_bounds__(256) void transpose_v(const u16* __restrict__ mixed,
                                                   u16* __restrict__ vb)
{
    __shared__ u16 tile[64][144];
    int bn = blockIdx.x >> 5, pt = blockIdx.x & 31;
    int p0 = pt * 64;
    int t = threadIdx.x;
    int nh = bn & 15;
    int hd8 = t & 15, pr = t >> 4;
    for (int i = 0; i < 4; i++) {
        int p = pr + i * 16;
        int pos = p0 + p;
        int b = pos >> 10, s = ((pos & 1023) << 1) | (bn >> 4);
        const u16* src = mixed + (size_t)(b * 2048 + s) * 6144 + nh * 384 + 256 + hd8 * 8;
        *(u16x8*)&tile[p][hd8 * 8] = *(const u16x8*)src;
    }
    __syncthreads();
    int hd = t >> 1, h2 = (t & 1) * 32;
    u16 tmp[32];
    for (int j = 0; j < 32; j++) tmp[j] = tile[h2 + j][hd];
    u16* dst = vb + (size_t)(bn * 128 + hd) * 2048 + p0 + h2;
    for (int i = 0; i < 4; i++) *(u16x8*)(dst + i * 8) = *(const u16x8*)&tmp[i * 8];
}

// ---------------------------------------------------------------------------
// flash attention in scrambled (bn, pos) space, causal, alibi[bn&15][k]
// Diagonal-paired: block (p, bn) handles Q tiles qt=p AND qt=31-p -> every
// block runs exactly 33 K-tile iterations (uniform duration, no tail).
// block = 4 waves, Q tile 64 rows (16/wave), K tiles of 64
// writes ctx bf16 [pos*2 + bn>>4][ (bn&15)*128 + hd ]  (rows of dense GEMM)
// ---------------------------------------------------------------------------
__global__ __launch_bounds__(256) void attn(
    const u16* __restrict__ qb, const u16* __restrict__ kb,
    const u16* __restrict__ vb, const float* __restrict__ alibi,
    u16* __restrict__ ctx)
{
    __shared__ u16 Ks[64 * 136];    // K tile [k][hd], pad 136 (uniform banks)
    __shared__ u16 Vt[128 * 88];    // V^T tile [hd][k], pad 88 (uniform banks)
    __shared__ u16 Ps[64 * 88];     // P tile [q][k], pad 88 (was 80: 4-way conflict)

    int bn = blockIdx.y;
    int tid = threadIdx.x, wave = tid >> 6, lane = tid & 63;
    int lg = lane >> 4, lm = lane & 15;

    const float* al = alibi + (bn & 15) * 2048;

    int krow = tid >> 2, kq = (tid & 3) * 32;
    int vhd  = tid >> 1, vh2 = (tid & 1) * 32;
    const u16* ksrc0 = kb + (size_t)(bn * 2048 + krow) * 128 + kq;
    const u16* vsrc0 = vb + (size_t)(bn * 128 + vhd) * 2048 + vh2;

    for (int pass = 0; pass < 2; pass++) {
        int qt = pass ? (31 - blockIdx.x) : blockIdx.x;
        int q0 = qt * 64;

        // Q fragments (pre-scaled bf16), wave owns rows q0+16w .. +15
        bf16x8 qf[4];
        {
            const u16* qp = qb + (size_t)(bn * 2048 + q0 + wave * 16 + lm) * 128;
            for (int kc = 0; kc < 4; kc++) qf[kc] = *(const bf16x8*)(qp + kc * 32 + lg * 8);
        }

        f32x4 o[8];
        for (int i = 0; i < 8; i++) o[i] = (f32x4){0.f, 0.f, 0.f, 0.f};
        float m_i[4] = {-3e38f, -3e38f, -3e38f, -3e38f};
        float l_i[4] = {0.f, 0.f, 0.f, 0.f};

        for (int kt = 0; kt <= qt; kt++) {
            int k0 = kt * 64;
            __syncthreads();
            {   // stage K [64][128] and V^T [128][64]
                const u16* s1 = ksrc0 + (size_t)k0 * 128;
                u16* d1 = &Ks[krow * 136 + kq];
                for (int i = 0; i < 4; i++) *(u16x8*)(d1 + i * 8) = *(const u16x8*)(s1 + i * 8);
                const u16* s2 = vsrc0 + k0;
                u16* d2 = &Vt[vhd * 88 + vh2];
                for (int i = 0; i < 4; i++) *(u16x8*)(d2 + i * 8) = *(const u16x8*)(s2 + i * 8);
            }
            __syncthreads();

            // S = Qs * K^T  (per wave: 16 q rows x 64 k cols)
            f32x4 sc[4];
            for (int tc = 0; tc < 4; tc++) {
                f32x4 a = (f32x4){0.f, 0.f, 0.f, 0.f};
                const u16* kr = &Ks[(tc * 16 + lm) * 136];
                for (int kc = 0; kc < 4; kc++) {
                    bf16x8 bfr = *(const bf16x8*)(kr + kc * 32 + lg * 8);
                    a = __builtin_amdgcn_mfma_f32_16x16x32_bf16(qf[kc], bfr, a, 0, 0, 0);
                }
                sc[tc] = a;
            }
            // alibi + causal mask
            for (int tc = 0; tc < 4; tc++) {
                int kg = k0 + tc * 16 + lm;
                float av = al[kg];
                for (int r = 0; r < 4; r++) {
                    float v = sc[tc][r] + av;
                    if (kt == qt) {
                        int qg = q0 + wave * 16 + lg * 4 + r;
                        if (kg > qg) v = -3e38f;
                    }
                    sc[tc][r] = v;
                }
            }
            // online softmax (row lives in 16 consecutive lanes, same lg)
            float alpha[4];
            for (int r = 0; r < 4; r++) {
                float t = fmaxf(fmaxf(sc[0][r], sc[1][r]), fmaxf(sc[2][r], sc[3][r]));
                t = fmaxf(t, __shfl_xor(t, 1));
                t = fmaxf(t, __shfl_xor(t, 2));
                t = fmaxf(t, __shfl_xor(t, 4));
                t = fmaxf(t, __shfl_xor(t, 8));
                float mn = fmaxf(m_i[r], t);
                alpha[r] = __expf(m_i[r] - mn);
                m_i[r] = mn;
            }
            for (int r = 0; r < 4; r++) {
                float rs = 0.f;
                for (int tc = 0; tc < 4; tc++) {
                    float p = __expf(sc[tc][r] - m_i[r]);
                    sc[tc][r] = p;
                    rs += p;
                }
                rs += __shfl_xor(rs, 1);
                rs += __shfl_xor(rs, 2);
                rs += __shfl_xor(rs, 4);
                rs += __shfl_xor(rs, 8);
                l_i[r] = l_i[r] * alpha[r] + rs;
            }
            for (int i = 0; i < 8; i++)
                for (int r = 0; r < 4; r++) o[i][r] *= alpha[r];

            // P -> LDS (C/D layout -> A-operand layout round trip)
            for (int tc = 0; tc < 4; tc++)
                for (int r = 0; r < 4; r++)
                    Ps[(wave * 16 + lg * 4 + r) * 88 + tc * 16 + lm] = f2b(sc[tc][r]);
            __syncthreads();

            // O += P * V
            for (int kc = 0; kc < 2; kc++) {
                bf16x8 pf = *(const bf16x8*)&Ps[(wave * 16 + lm) * 88 + kc * 32 + lg * 8];
                for (int i = 0; i < 8; i++) {
                    bf16x8 vf = *(const bf16x8*)&Vt[(i * 16 + lm) * 88 + kc * 32 + lg * 8];
                    o[i] = __builtin_amdgcn_mfma_f32_16x16x32_bf16(pf, vf, o[i], 0, 0, 0);
                }
            }
        }

        // epilogue: ctx[pos*2 + b'][ nh'*128 + hd ]  (reference keeps scrambled coords)
        for (int r = 0; r < 4; r++) {
            float inv = 1.0f / l_i[r];
            int qg = q0 + wave * 16 + lg * 4 + r;
            int row = qg * 2 + (bn >> 4);
            u16* crow = ctx + (size_t)row * 2048 + (bn & 15) * 128;
            for (int i = 0; i < 8; i++)
                crow[i * 16 + lm] = f2b(o[i][r] * inv);
        }
    }
}

// ---------------------------------------------------------------------------
// launch
// ---------------------------------------------------------------------------
extern "C" void kernel_launch(void* const* d_in, const int* in_sizes, int n_in,
                              void* d_out, int out_size, void* d_ws, size_t ws_size,
                              hipStream_t stream)
{
    const float* hs    = (const float*)d_in[0];   // [2,2048,2048]
    const float* alibi = (const float*)d_in[1];   // [16,1,2048]
    const float* wqkv  = (const float*)d_in[2];   // [6144,2048]
    const float* bqkv  = (const float*)d_in[3];   // [6144]
    const float* wd    = (const float*)d_in[4];   // [2048,2048]
    const float* bd    = (const float*)d_in[5];   // [2048]
    float* out = (float*)d_out;                   // [2,2048,2048] f32

    char* ws = (char*)d_ws;
    u16* wqkv_b = (u16*)(ws + 0);            // 12,582,912 elems (25,165,824 B)
    u16* hs_b   = (u16*)(ws + 25165824);     //  8,388,608 elems (16,777,216 B)
    u16* mixed  = (u16*)(ws + 41943040);     // 25,165,824 elems (50,331,648 B)
    u16* ctx    = mixed;                     // alias: mixed dead after scatter
    u16* wd_b   = wqkv_b;                    // alias: wqkv dead after gemm1
    u16* qb     = (u16*)(ws + 92274688);     // [32][2048][128] bf16
    u16* kb     = (u16*)(ws + 109051904);
    u16* vb     = (u16*)(ws + 125829120);    // end = 142,606,336 B

    cvt_f32_bf16<<<8192,  256, 0, stream>>>(hs,   hs_b,   2097152);
    cvt_f32_bf16<<<12288, 256, 0, stream>>>(wqkv, wqkv_b, 3145728);

    // mixed = hs @ wqkv^T + bqkv   (M=4096, N=6144, K=2048)
    gemm_bt<<<dim3(48, 32), 256, 0, stream>>>(hs_b, wqkv_b, bqkv, mixed, 4096, 6144, 2048, 0);

    scatter_qk<<<dim3(4096, 2), 256, 0, stream>>>(mixed, qb, kb);
    transpose_v<<<1024, 256, 0, stream>>>(mixed, vb);
    cvt_f32_bf16<<<4096, 256, 0, stream>>>(wd, wd_b, 1048576);

    // diagonal-paired flash attention: 16 x 32 uniform blocks
    attn<<<dim3(16, 32), 256, 0, stream>>>(qb, kb, vb, alibi, ctx);

    // out = ctx @ wd^T + bd, rows remapped to [b][s][h]   (M=4096, N=2048, K=2048)
    gemm_bt<<<dim3(16, 32), 256, 0, stream>>>(ctx, wd_b, bd, out, 4096, 2048, 2048, 1);
}